// Round 1
// baseline (222.647 us; speedup 1.0000x reference)
//
#include <hip/hip_runtime.h>

#define VGRID 256
#define N_TAPS 27
#define CIN 64
#define COUT 64

typedef short short8 __attribute__((ext_vector_type(8)));   // 8 bf16
typedef float float4v __attribute__((ext_vector_type(4)));  // MFMA C/D

__device__ __forceinline__ short f2bf(float x) {
    unsigned u = __builtin_bit_cast(unsigned, x);
    unsigned r = (u + 0x7FFF + ((u >> 16) & 1)) >> 16;  // RNE
    return (short)r;
}

// Table scatter (signed atomicMax beats 0xAA poison; no table init needed)
// + occupancy bitmap + fused weight conversion into FRAGMENT-MAJOR layout:
// Wt[tap][ks][quad][cout][8] so a B-fragment is one contiguous 16B load.
__global__ void __launch_bounds__(256) build_kernel(
        const int* __restrict__ coords, int* __restrict__ table,
        unsigned* __restrict__ bits, const float* __restrict__ W,
        short* __restrict__ Wt, int n, int bt_blocks) {
    if ((int)blockIdx.x >= bt_blocks) {
        int tap = blockIdx.x - bt_blocks;
        for (int e = threadIdx.x; e < CIN * COUT; e += 256) {
            int ci = e >> 6, co = e & 63;
            int ks = ci >> 5, quad = (ci >> 3) & 3, el = ci & 7;
            Wt[((((size_t)tap * 2 + ks) * 4 + quad) * 64 + co) * 8 + el] =
                f2bf(W[((size_t)tap * CIN + ci) * COUT + co]);
        }
        return;
    }
    int i = blockIdx.x * 256 + threadIdx.x;
    if (i >= n) return;
    int lin = (coords[i * 3 + 0] * VGRID + coords[i * 3 + 1]) * VGRID + coords[i * 3 + 2];
    atomicMax(&table[lin], i);   // last-write-wins == max index (ref semantics)
    atomicOr(&bits[lin >> 5], 1u << (lin & 31));
}

// Fully fused gather-formulation conv: every contribution to out[i]
// (center + all 26 neighbor taps) computed by the wave owning row i.
// No LDS, no __syncthreads, no pair lists, no atomics on out.
// Wave owns 64 points = 4 groups of 16 rows; per group: center MFMAs +
// per-active-tap MFMAs with register-gathered A (zero rows where no hit),
// chained into one f32 accumulator, stored once.
__global__ void __launch_bounds__(256) fused_kernel(
        const int* __restrict__ coords, const int* __restrict__ table,
        const unsigned* __restrict__ bits, const float* __restrict__ feats,
        const short* __restrict__ Wt, float* __restrict__ out, int n) {
    int t = threadIdx.x;
    int lane = t & 63;
    int i = blockIdx.x * 256 + t;
    int wbase = blockIdx.x * 256 + (t & 192);   // wave's first point

    // ---- phase 1: per-thread probe of own point (bitmap-gated) ----
    int cx = 0, cy = 0, cz = 0;
    unsigned hitmask = 0;
    int center_idx = 0;
    if (i < n) {
        cx = coords[i * 3 + 0];
        cy = coords[i * 3 + 1];
        cz = coords[i * 3 + 2];
        int clin = (cx * VGRID + cy) * VGRID + cz;
        center_idx = table[clin];    // own voxel: always set this launch

        // 18 bitmap loads (9 (x,y)-rows x word pair covering z-1..z+1)
        int zlo = cz > 0 ? cz - 1 : 0;
        int zhi = cz < VGRID - 1 ? cz + 1 : VGRID - 1;
        int wlo = zlo >> 5, whi = zhi >> 5;
        unsigned rw0[9], rw1[9];
#pragma unroll
        for (int r = 0; r < 9; ++r) {
            int nx = cx + r / 3 - 1, ny = cy + r % 3 - 1;
            bool v = ((unsigned)nx < VGRID) && ((unsigned)ny < VGRID);
            int rb = ((nx * VGRID + ny) * VGRID) >> 5;   // word index of z-row base
            rw0[r] = v ? bits[rb + wlo] : 0u;
            rw1[r] = v ? bits[rb + whi] : 0u;
        }
#pragma unroll
        for (int k = 0; k < N_TAPS; ++k) {
            if (k == 13) continue;
            int nz = cz + k % 3 - 1;
            if ((unsigned)nz < VGRID) {
                unsigned wrd = ((nz >> 5) == wlo) ? rw0[k / 3] : rw1[k / 3];
                hitmask |= ((wrd >> (nz & 31)) & 1u) << k;
            }
        }
    }

    // prefetch j for first 4 hits (ctz order; rank>=4 reloads lazily)
    int p0 = 0, p1 = 0, p2 = 0, p3 = 0;
    {
        unsigned hm = hitmask;
        int cnt = 0;
        while (hm) {
            int k = __builtin_ctz(hm); hm &= hm - 1u;
            int nlin = ((cx + k / 9 - 1) * VGRID + (cy + (k / 3) % 3 - 1)) * VGRID
                       + (cz + k % 3 - 1);
            int j = table[nlin];
            if (cnt == 0) p0 = j; else if (cnt == 1) p1 = j;
            else if (cnt == 2) p2 = j; else if (cnt == 3) p3 = j;
            ++cnt;
        }
    }

    int packed = (cx << 16) | (cy << 8) | cz;   // coords fit 8 bits each

    // OR of hitmasks over each 16-lane group (wave-synchronous shuffles)
    unsigned gmor = hitmask;
    gmor |= (unsigned)__shfl_xor((int)gmor, 1);
    gmor |= (unsigned)__shfl_xor((int)gmor, 2);
    gmor |= (unsigned)__shfl_xor((int)gmor, 4);
    gmor |= (unsigned)__shfl_xor((int)gmor, 8);

    // ---- phase 2: GEMM, wave-independent, zero barriers ----
    int m = lane & 15, quad = lane >> 4;
    const short8* Bp = (const short8*)Wt;

    for (int g = 0; g < 4; ++g) {
        int src = g * 16 + m;
        int rpk = __shfl(packed, src);
        unsigned rhm = (unsigned)__shfl((int)hitmask, src);
        int rjc = __shfl(center_idx, src);
        int rp0 = __shfl(p0, src), rp1 = __shfl(p1, src);
        int rp2 = __shfl(p2, src), rp3 = __shfl(p3, src);
        unsigned gor = (unsigned)__shfl((int)gmor, g * 16);
        gor = __builtin_amdgcn_readfirstlane(gor);

        float4v acc[4] = {{0,0,0,0},{0,0,0,0},{0,0,0,0},{0,0,0,0}};

        // center tap (13): A gathered straight to registers
        {
            const float* fr = feats + (size_t)rjc * CIN + quad * 8;
            float4 u0 = *(const float4*)(fr);
            float4 u1 = *(const float4*)(fr + 4);
            float4 v0 = *(const float4*)(fr + 32);
            float4 v1 = *(const float4*)(fr + 36);
            short8 a0 = {f2bf(u0.x), f2bf(u0.y), f2bf(u0.z), f2bf(u0.w),
                         f2bf(u1.x), f2bf(u1.y), f2bf(u1.z), f2bf(u1.w)};
            short8 a1 = {f2bf(v0.x), f2bf(v0.y), f2bf(v0.z), f2bf(v0.w),
                         f2bf(v1.x), f2bf(v1.y), f2bf(v1.z), f2bf(v1.w)};
#pragma unroll
            for (int nt = 0; nt < 4; ++nt) {
                short8 b0 = Bp[((13 * 2 + 0) * 4 + quad) * 64 + nt * 16 + m];
                short8 b1 = Bp[((13 * 2 + 1) * 4 + quad) * 64 + nt * 16 + m];
                acc[nt] = __builtin_amdgcn_mfma_f32_16x16x32_bf16(a0, b0, acc[nt], 0, 0, 0);
                acc[nt] = __builtin_amdgcn_mfma_f32_16x16x32_bf16(a1, b1, acc[nt], 0, 0, 0);
            }
        }

        // neighbor taps present anywhere in this 16-row group
        unsigned gm = gor;
        while (gm) {
            int k = (int)__builtin_ctz(gm); gm &= gm - 1u;
            bool has = (rhm >> k) & 1u;
            short8 h0 = {0,0,0,0,0,0,0,0}, h1 = {0,0,0,0,0,0,0,0};
            if (has) {
                int rank = __builtin_popcount(rhm & ((1u << k) - 1u));
                int j2;
                if (rank == 0) j2 = rp0;
                else if (rank == 1) j2 = rp1;
                else if (rank == 2) j2 = rp2;
                else if (rank == 3) j2 = rp3;
                else {
                    int rx = (rpk >> 16) & 255, ry = (rpk >> 8) & 255, rz = rpk & 255;
                    j2 = table[((rx + k / 9 - 1) * VGRID + (ry + (k / 3) % 3 - 1)) * VGRID
                               + (rz + k % 3 - 1)];
                }
                const float* hr = feats + (size_t)j2 * CIN + quad * 8;
                float4 u0 = *(const float4*)(hr);
                float4 u1 = *(const float4*)(hr + 4);
                float4 v0 = *(const float4*)(hr + 32);
                float4 v1 = *(const float4*)(hr + 36);
                h0 = (short8){f2bf(u0.x), f2bf(u0.y), f2bf(u0.z), f2bf(u0.w),
                              f2bf(u1.x), f2bf(u1.y), f2bf(u1.z), f2bf(u1.w)};
                h1 = (short8){f2bf(v0.x), f2bf(v0.y), f2bf(v0.z), f2bf(v0.w),
                              f2bf(v1.x), f2bf(v1.y), f2bf(v1.z), f2bf(v1.w)};
            }
#pragma unroll
            for (int nt = 0; nt < 4; ++nt) {
                short8 b0 = Bp[((k * 2 + 0) * 4 + quad) * 64 + nt * 16 + m];
                short8 b1 = Bp[((k * 2 + 1) * 4 + quad) * 64 + nt * 16 + m];
                acc[nt] = __builtin_amdgcn_mfma_f32_16x16x32_bf16(h0, b0, acc[nt], 0, 0, 0);
                acc[nt] = __builtin_amdgcn_mfma_f32_16x16x32_bf16(h1, b1, acc[nt], 0, 0, 0);
            }
        }

        // store 16x64 tile, written exactly once, non-atomic
#pragma unroll
        for (int nt = 0; nt < 4; ++nt)
#pragma unroll
            for (int r2 = 0; r2 < 4; ++r2) {
                int orow = wbase + g * 16 + quad * 4 + r2;
                if (orow < n) out[(size_t)orow * COUT + nt * 16 + m] = acc[nt][r2];
            }
    }
}

extern "C" void kernel_launch(void* const* d_in, const int* in_sizes, int n_in,
                              void* d_out, int out_size, void* d_ws, size_t ws_size,
                              hipStream_t stream) {
    const int* coords = (const int*)d_in[0];
    const float* feats = (const float*)d_in[1];
    const float* weights = (const float*)d_in[2];
    float* out = (float*)d_out;

    int n = in_sizes[0] / 3;  // 262144

    // workspace layout: bits @0 (2 MiB) | Wt @2 MiB (216 KiB) | table @4 MiB (64 MiB)
    char* ws = (char*)d_ws;
    size_t BITMAP_BYTES = (size_t)VGRID * VGRID * VGRID / 8;   // 2 MiB
    unsigned* bits = (unsigned*)ws;
    short* wbft = (short*)(ws + BITMAP_BYTES);
    int* table = (int*)(ws + ((size_t)4 << 20));               // never cleared

    // clear bitmap only; table: signed atomicMax beats 0xAA poison, and
    // probe reads only bitmap-set voxels (all written this launch)
    hipMemsetAsync(ws, 0, BITMAP_BYTES, stream);

    int bt_blocks = (n + 255) / 256;
    build_kernel<<<bt_blocks + N_TAPS, 256, 0, stream>>>(coords, table, bits,
                                                         weights, wbft, n, bt_blocks);

    fused_kernel<<<bt_blocks, 256, 0, stream>>>(coords, table, bits, feats,
                                                wbft, out, n);
}